// Round 5
// baseline (1777.228 us; speedup 1.0000x reference)
//
#include <hip/hip_runtime.h>

#define HH 32
#define LOG2E 1.44269504088896340736f

// ds_swizzle BitMode xor patterns (within 32-lane groups)
#define SWZ(v, pat) __int_as_float(__builtin_amdgcn_ds_swizzle(__float_as_int(v), (pat)))

__device__ __forceinline__ float hw_exp2(float x) {
    float r;
    asm("v_exp_f32 %0, %1" : "=v"(r) : "v"(x));   // guaranteed HW exp2
    return r;
}
__device__ __forceinline__ float sigm_e(float z, float escale) {
    // 1/(1 + exp2(z*escale)); sigmoid(z) when escale = -log2(e)
    return __builtin_amdgcn_rcpf(1.0f + hw_exp2(z * escale));
}
__device__ __forceinline__ float rlane(float v, int l) {
    return __int_as_float(__builtin_amdgcn_readlane(__float_as_int(v), l));
}

__global__ __launch_bounds__(128, 2)
void lstm_seq_kernel(const float* __restrict__ input,
                     const float* __restrict__ W_ih1, const float* __restrict__ W_hh1,
                     const float* __restrict__ b_ih1, const float* __restrict__ b_hh1,
                     const float* __restrict__ W_ih2, const float* __restrict__ W_hh2,
                     const float* __restrict__ b_ih2, const float* __restrict__ b_hh2,
                     const float* __restrict__ W_lin, const float* __restrict__ b_lin,
                     float* __restrict__ out, int T, int total)
{
    const int b    = blockIdx.x;     // one block (2 waves) per batch element
    const int tid  = threadIdx.x;    // 0..127 == gate row (i:0-31 f:32-63 g:64-95 o:96-127)
    const int lane = tid & 63;
    const int ch   = lane & 31;      // channel this lane redundantly tracks
    const int gate = tid >> 5;       // 0=i 1=f 2=g 3=o

    __shared__ float g1buf[128];     // cell-1 activations, one slot per gate row
    __shared__ float g2buf[128];     // cell-2 activations

    // ---- resident weights: 3 rows x 32 = 96 floats/lane (minimum possible) ----
    float wh1[HH], wi2[HH], wh2[HH];
    {
        const float4* p1 = (const float4*)(W_hh1 + tid * HH);
        const float4* p2 = (const float4*)(W_ih2 + tid * HH);
        const float4* p3 = (const float4*)(W_hh2 + tid * HH);
#pragma unroll
        for (int r = 0; r < HH / 4; ++r) {
            float4 v;
            v = p1[r]; wh1[4*r] = v.x; wh1[4*r+1] = v.y; wh1[4*r+2] = v.z; wh1[4*r+3] = v.w;
            v = p2[r]; wi2[4*r] = v.x; wi2[4*r+1] = v.y; wi2[4*r+2] = v.z; wi2[4*r+3] = v.w;
            v = p3[r]; wh2[4*r] = v.x; wh2[4*r+1] = v.y; wh2[4*r+2] = v.z; wh2[4*r+3] = v.w;
        }
    }
    const float wx   = W_ih1[tid];
    const float b1   = b_ih1[tid] + b_hh1[tid];
    const float b2   = b_ih2[tid] + b_hh2[tid];
    const float wl   = W_lin[ch];
    const float blin = b_lin[0];

    // gate g uses tanh(z) = 2*sigmoid(2z)-1; i/f/o use sigmoid
    const bool  isg = (gate == 2);
    const float es  = isg ? (-2.0f * LOG2E) : (-LOG2E);
    const float mm  = isg ? 2.0f : 1.0f;
    const float cc  = isg ? -1.0f : 0.0f;

    float c1 = 0.0f, c2 = 0.0f;      // state for ch, redundantly on every lane
    float ov = 0.0f;                 // previous output (all lanes, feedback)
    // carried partials: ca = b1 + Wh1·h1(t-1), ce = b2 + Wh2·h2(t-1)
    float ca0 = b1, ca1 = 0.0f;
    float ce0 = b2, ce1 = 0.0f;

    const float* __restrict__ inp  = input + (size_t)b * T;
    float* __restrict__       outp = out   + (size_t)b * total;

    for (int t = 0; t < total; ++t) {
        float xin = inp[t < T ? t : (T - 1)];    // uniform scalar load
        float x   = (t < T) ? xin : ov;

        // ---------- cell 1: z1 from carried partial ----------
        float z1  = fmaf(x, wx, ca0 + ca1);
        float a1v = fmaf(mm, sigm_e(z1, es), cc);    // sig(i/f/o) | tanh(g)
        g1buf[tid] = a1v;
        __syncthreads();                              // B1: cell-1 acts visible

        float si = g1buf[ch];                         // 2-way broadcast reads (free)
        float sf = g1buf[32 + ch];
        float tg = g1buf[64 + ch];
        float so = g1buf[96 + ch];
        c1 = fmaf(sf, c1, si * tg);
        float h1 = so * fmaf(2.0f, sigm_e(c1, -2.0f * LOG2E), -1.0f);  // tanh(c1)
        // h1(ch=k) lives on lane k (k<32) of BOTH waves -> readlane broadcast

        // ---------- fused: z2 accumulate (wi2·h1) + next z1 carry (wh1·h1) ----------
        float e0 = ce0, e1 = ce1;
        float a0 = b1,  a1 = 0.0f;
#pragma unroll
        for (int k = 0; k < HH; k += 2) {
            float hs0 = rlane(h1, k);
            float hs1 = rlane(h1, k + 1);
            e0 = fmaf(hs0, wi2[k],     e0);
            a0 = fmaf(hs0, wh1[k],     a0);
            e1 = fmaf(hs1, wi2[k + 1], e1);
            a1 = fmaf(hs1, wh1[k + 1], a1);
        }
        ca0 = a0; ca1 = a1;

        float z2  = e0 + e1;
        float a2v = fmaf(mm, sigm_e(z2, es), cc);
        g2buf[tid] = a2v;
        __syncthreads();                              // B2: cell-2 acts visible

        float si2 = g2buf[ch];
        float sf2 = g2buf[32 + ch];
        float tg2 = g2buf[64 + ch];
        float so2 = g2buf[96 + ch];
        c2 = fmaf(sf2, c2, si2 * tg2);
        float h2 = so2 * fmaf(2.0f, sigm_e(c2, -2.0f * LOG2E), -1.0f); // tanh(c2)

        // ---------- fused: next z2 carry (wh2·h2) + output dot ----------
        float f0 = b2, f1 = 0.0f;
#pragma unroll
        for (int k = 0; k < HH; k += 2) {
            float hs0 = rlane(h2, k);
            float hs1 = rlane(h2, k + 1);
            f0 = fmaf(hs0, wh2[k],     f0);
            f1 = fmaf(hs1, wh2[k + 1], f1);
        }
        ce0 = f0; ce1 = f1;

        float p = h2 * wl;                            // lane holds h2(ch)·wl(ch)
        p += SWZ(p, 0x041F);                          // xor1
        p += SWZ(p, 0x081F);                          // xor2
        p += SWZ(p, 0x101F);                          // xor4
        p += SWZ(p, 0x201F);                          // xor8
        p += SWZ(p, 0x401F);                          // xor16 -> sum over 32 channels
        ov = p + blin;                                // identical on all lanes
        if (tid == 0) outp[t] = ov;
    }
}

extern "C" void kernel_launch(void* const* d_in, const int* in_sizes, int n_in,
                              void* d_out, int out_size, void* d_ws, size_t ws_size,
                              hipStream_t stream) {
    const int B = 1024;                 // fixed by the source module
    const int T = in_sizes[0] / B;      // 999
    const int total = out_size / B;     // T + future = 1999

    lstm_seq_kernel<<<dim3(B), dim3(128), 0, stream>>>(
        (const float*)d_in[0],
        (const float*)d_in[1], (const float*)d_in[2],
        (const float*)d_in[3], (const float*)d_in[4],
        (const float*)d_in[5], (const float*)d_in[6],
        (const float*)d_in[7], (const float*)d_in[8],
        (const float*)d_in[9], (const float*)d_in[10],
        (float*)d_out, T, total);
}

// Round 6
// 1456.664 us; speedup vs baseline: 1.2201x; 1.2201x over previous
//
#include <hip/hip_runtime.h>

#define HH 32
#define LOG2E 1.44269504088896340736f

typedef float v2f __attribute__((ext_vector_type(2)));

// DPP quad_perm controls: xor within the 4-lane gate group (q = lane&3)
#define QP_XOR1 0xB1   // [1,0,3,2]
#define QP_XOR2 0x4E   // [2,3,0,1]
#define QP_XOR3 0x1B   // [3,2,1,0]
#define QPERM(v, ctrl) \
    __int_as_float(__builtin_amdgcn_update_dpp(0, __float_as_int(v), (ctrl), 0xF, 0xF, true))

__device__ __forceinline__ float hw_exp2(float x) {
    float r;
    asm("v_exp_f32 %0, %1" : "=v"(r) : "v"(x));   // guaranteed HW exp2
    return r;
}
__device__ __forceinline__ float sigm_e(float z, float escale) {
    // 1/(1 + exp2(z*escale)); sigmoid(z) when escale = -log2(e)
    return __builtin_amdgcn_rcpf(1.0f + hw_exp2(z * escale));
}
// guaranteed packed f32 FMA: d = a*b + c (2 lanes-of-2 per instruction)
__device__ __forceinline__ v2f pk_fma(v2f a, v2f b, v2f c) {
    v2f d;
    asm("v_pk_fma_f32 %0, %1, %2, %3" : "=v"(d) : "v"(a), "v"(b), "v"(c));
    return d;
}

__global__ __launch_bounds__(128, 2)
void lstm_seq_kernel(const float* __restrict__ input,
                     const float* __restrict__ W_ih1, const float* __restrict__ W_hh1,
                     const float* __restrict__ b_ih1, const float* __restrict__ b_hh1,
                     const float* __restrict__ W_ih2, const float* __restrict__ W_hh2,
                     const float* __restrict__ b_ih2, const float* __restrict__ b_hh2,
                     const float* __restrict__ W_lin, const float* __restrict__ b_lin,
                     float* __restrict__ out, int T, int total)
{
    const int b    = blockIdx.x;     // one block (2 waves) per batch element
    const int tid  = threadIdx.x;    // 0..127
    const int w    = tid >> 6;       // wave 0/1
    const int lane = tid & 63;
    const int q    = lane & 3;       // gate: 0=i 1=f 2=g 3=o (quad_perm neighbors)
    const int m    = lane >> 2;      // channel-within-wave 0..15
    const int j    = (w << 4) | m;   // channel 0..31
    const int row  = (q << 5) | j;   // gate row 0..127 (PyTorch i,f,g,o blocks)

    __shared__ __align__(16) float h1buf[HH];
    __shared__ __align__(16) float h2buf[HH];

    // ---- resident weights as float2: 4 arrays x 16 pairs = 128 floats/lane ----
    v2f wh1v[16], wi2v[16], wh2v[16], wlv[16];
    {
        const v2f* p1 = (const v2f*)(W_hh1 + row * HH);
        const v2f* p2 = (const v2f*)(W_ih2 + row * HH);
        const v2f* p3 = (const v2f*)(W_hh2 + row * HH);
        const v2f* p4 = (const v2f*)(W_lin);            // replicated on all lanes
#pragma unroll
        for (int r = 0; r < 16; ++r) {
            wh1v[r] = p1[r]; wi2v[r] = p2[r]; wh2v[r] = p3[r]; wlv[r] = p4[r];
        }
    }
    const float wx   = W_ih1[row];
    const float b1   = b_ih1[row] + b_hh1[row];
    const float b2   = b_ih2[row] + b_hh2[row];
    const float blin = b_lin[0];

    // gate g (q==2) uses tanh = 2*sigmoid(2z)-1; i/f/o use sigmoid
    const bool  isg = (q == 2);
    const float es  = isg ? (-2.0f * LOG2E) : (-LOG2E);
    const float mm  = isg ? 2.0f : 1.0f;
    const float cc  = isg ? -1.0f : 0.0f;

    float c1 = 0.0f, c2 = 0.0f;      // valid on q==0 lanes (others harmless garbage)
    float ov = 0.0f;                 // previous output (all lanes, feedback)
    // carried partials: a = b1 + Wh1*h1(t-1), e = b2 + Wh2*h2(t-1), as packed pairs
    v2f a01 = {b1, 0.0f}, a23 = {0.0f, 0.0f};
    v2f e01 = {b2, 0.0f}, e23 = {0.0f, 0.0f};

    const float* __restrict__ inp  = input + (size_t)b * T;
    float* __restrict__       outp = out   + (size_t)b * total;

    for (int t = 0; t < total; ++t) {
        float xin = inp[t < T ? t : (T - 1)];    // uniform load
        float x   = (t < T) ? xin : ov;          // autoregressive feedback in-reg

        // ---------- P0: z1 from carried partial (short critical path) ----------
        float z1  = fmaf(x, wx, (a01.x + a01.y) + (a23.x + a23.y));
        float act = fmaf(mm, sigm_e(z1, es), cc);       // sig(i/f/o) | tanh(g)
        float vf  = QPERM(act, QP_XOR1);                // q=0 lane: gate f
        float vg  = QPERM(act, QP_XOR2);                // q=0 lane: gate g
        float vo  = QPERM(act, QP_XOR3);                // q=0 lane: gate o
        c1 = fmaf(vf, c1, act * vg);
        float h1 = vo * fmaf(2.0f, sigm_e(c1, -2.0f * LOG2E), -1.0f);  // tanh(c1)
        if (q == 0) h1buf[j] = h1;

        __syncthreads();                                 // B1: h1 visible

        // ---------- P1: one h1 read feeds BOTH z2 and next-step's z1 partial ----
        v2f hv[16];
#pragma unroll
        for (int r = 0; r < 8; ++r) {
            float4 v = ((const float4*)h1buf)[r];
            hv[2*r]   = (v2f){v.x, v.y};
            hv[2*r+1] = (v2f){v.z, v.w};
        }
        a01 = (v2f){b1, 0.0f}; a23 = (v2f){0.0f, 0.0f};
#pragma unroll
        for (int r = 0; r < 16; r += 2) {
            e01 = pk_fma(hv[r],   wi2v[r],   e01);
            e23 = pk_fma(hv[r+1], wi2v[r+1], e23);
            a01 = pk_fma(hv[r],   wh1v[r],   a01);
            a23 = pk_fma(hv[r+1], wh1v[r+1], a23);
        }
        {
            float z2   = (e01.x + e01.y) + (e23.x + e23.y);
            float act2 = fmaf(mm, sigm_e(z2, es), cc);
            float vf2  = QPERM(act2, QP_XOR1);
            float vg2  = QPERM(act2, QP_XOR2);
            float vo2  = QPERM(act2, QP_XOR3);
            c2 = fmaf(vf2, c2, act2 * vg2);
            float h2 = vo2 * fmaf(2.0f, sigm_e(c2, -2.0f * LOG2E), -1.0f); // tanh(c2)
            if (q == 0) h2buf[j] = h2;
        }

        __syncthreads();                                 // B2: h2 visible

        // ---------- P2: one h2 read feeds BOTH next z2 partial and the output ----
        v2f gv[16];
#pragma unroll
        for (int r = 0; r < 8; ++r) {
            float4 v = ((const float4*)h2buf)[r];
            gv[2*r]   = (v2f){v.x, v.y};
            gv[2*r+1] = (v2f){v.z, v.w};
        }
        e01 = (v2f){b2, 0.0f}; e23 = (v2f){0.0f, 0.0f};
        v2f o01 = {blin, 0.0f}, o23 = {0.0f, 0.0f};
#pragma unroll
        for (int r = 0; r < 16; r += 2) {
            e01 = pk_fma(gv[r],   wh2v[r],   e01);
            e23 = pk_fma(gv[r+1], wh2v[r+1], e23);
            o01 = pk_fma(gv[r],   wlv[r],    o01);
            o23 = pk_fma(gv[r+1], wlv[r+1],  o23);
        }
        ov = (o01.x + o01.y) + (o23.x + o23.y);          // all lanes, redundantly
        if (tid == 0) outp[t] = ov;
    }
}

extern "C" void kernel_launch(void* const* d_in, const int* in_sizes, int n_in,
                              void* d_out, int out_size, void* d_ws, size_t ws_size,
                              hipStream_t stream) {
    const int B = 1024;                 // fixed by the source module
    const int T = in_sizes[0] / B;      // 999
    const int total = out_size / B;     // T + future = 1999

    lstm_seq_kernel<<<dim3(B), dim3(128), 0, stream>>>(
        (const float*)d_in[0],
        (const float*)d_in[1], (const float*)d_in[2],
        (const float*)d_in[3], (const float*)d_in[4],
        (const float*)d_in[5], (const float*)d_in[6],
        (const float*)d_in[7], (const float*)d_in[8],
        (const float*)d_in[9], (const float*)d_in[10],
        (float*)d_out, T, total);
}